// Round 1
// baseline (424.992 us; speedup 1.0000x reference)
//
#include <hip/hip_runtime.h>

// CapsClass2d dynamic routing — MFMA (bf16) restructure, atomic-free merge.
// b=256, P=1152, C=10, os=is=16, 3 iterations.
// logits telescope: logits_k = dot(sum_{j<k} v_j, votes) -> only vsum state.
//
// votes[p] = W_p[160x16] @ X_p[16x256] via mfma_f32_16x16x32_bf16 (K padded).
//   A[m=o][k=i]: m=lane&15, k=quad*8+j (quads 2,3 zero)
//   B[k=i][n=b]: n=lane&15, k=quad*8+j
//   C/D: col(b)=lane&15, row(o)=quad*4+reg            [verified layouts, m89/m120]
// Wave = 16 batches x all 10 c x PW=3 positions; block = 4 waves, same b-tile.
// Grid (PBLK=96, 16 b-tiles) = 1536 blocks -> ~6 blocks/CU (was 2: grid-limited
// occupancy at 19.5%).
// Merge: per-block LDS (+1 pad) -> PLAIN STORES to a private partial slice
// (part[px][b][j]); squash kernel reduces the 96 partials. Replaces 1.31M
// memory-side fadd atomics (~79 MB HBM write-through per dispatch, the measured
// bottleneck) with 15.7 MB of streaming stores.
// it=0: coup=0.1 exactly -> MFMA accumulator chains over p (pure MFMA stream).
// Weight/poses pre-converted once to bf16 frag layout in ws (fallback: in-kernel).

#define NPOS 1152
#define NC 10
#define OS 16
#define IS 16
#define NB 256
#define CO (NC * OS)            // 160
#define CAPS_EPS 1e-8f
#define PW 3                    // positions per wave
#define PBLK (NPOS / (4 * PW))  // 96 p-superblocks
#define NA_SLOTS (NPOS * NC * 32)   // 368640 A-frag lane slots
#define NB_SLOTS (NPOS * 16 * 32)   // 589824 B-frag lane slots

typedef __attribute__((ext_vector_type(8))) short bf16x8;
typedef __attribute__((ext_vector_type(4))) float floatx4;

__device__ __forceinline__ unsigned f2bf_rne(float x) {
    union { float f; unsigned u; } v; v.f = x;
    return (v.u + 0x7FFFu + ((v.u >> 16) & 1u)) >> 16;
}

__device__ __forceinline__ bf16x8 pack8(float4 a, float4 b) {
    union { unsigned u[4]; bf16x8 v; } r;
    r.u[0] = f2bf_rne(a.x) | (f2bf_rne(a.y) << 16);
    r.u[1] = f2bf_rne(a.z) | (f2bf_rne(a.w) << 16);
    r.u[2] = f2bf_rne(b.x) | (f2bf_rne(b.y) << 16);
    r.u[3] = f2bf_rne(b.z) | (f2bf_rne(b.w) << 16);
    return r.v;
}

__device__ __forceinline__ bf16x8 zero8() {
    union { unsigned u[4]; bf16x8 v; } r;
    r.u[0] = r.u[1] = r.u[2] = r.u[3] = 0u;
    return r.v;
}

__device__ __forceinline__ bf16x8 load8(const uint4* p) {
    union { uint4 u; bf16x8 v; } r; r.u = *p; return r.v;
}

// Pre-convert W and poses into bf16 fragment-layout buffers.
__global__ __launch_bounds__(256) void preconv_kernel(
    const float* __restrict__ poses, const float* __restrict__ weight,
    uint4* __restrict__ wsA, uint4* __restrict__ wsB)
{
    const int gid = blockIdx.x * 256 + threadIdx.x;
    if (gid < NA_SLOTS) {
        const int L = gid & 31, pc = gid >> 5;          // pc = p*10+c
        const int o = L & 15, q = L >> 4;
        const float4* src = (const float4*)(weight + (size_t)pc * 256 + o * 16 + q * 8);
        uint4 d; union { uint4 u; bf16x8 v; } cv;
        cv.v = pack8(src[0], src[1]); d = cv.u;
        wsA[gid] = d;
    } else {
        const int s = gid - NA_SLOTS;
        if (s < NB_SLOTS) {
            const int L = s & 31, pb = s >> 5;
            const int bt = pb & 15, p = pb >> 4;
            const int bl = L & 15, q = L >> 4;
            const float4* src = (const float4*)(poses +
                ((size_t)(bt * 16 + bl) * NPOS + p) * IS + q * 8);
            union { uint4 u; bf16x8 v; } cv;
            cv.v = pack8(src[0], src[1]);
            wsB[s] = cv.u;
        }
    }
}

// PART=true: sbuf is part[PBLK][NB][CO], block writes its own slice (no atomics).
// PART=false: legacy global-atomic merge into sbuf[NB][CO].
template <bool PC, bool PART>
__global__ __launch_bounds__(256, 3) void caps_votes_mfma(
    const float* __restrict__ poses, const float* __restrict__ weight,
    const uint4* __restrict__ wsA, const uint4* __restrict__ wsB,
    const float* __restrict__ vsum, float* __restrict__ sbuf,
    float* __restrict__ out_coup, int it)
{
    const int t    = threadIdx.x;
    const int wave = t >> 6, lane = t & 63;
    const int bcol = lane & 15, quad = lane >> 4;
    const int bt   = blockIdx.y;          // b-tile (16 batches)
    const int b0   = bt * 16;
    const int pbase = blockIdx.x * (4 * PW) + wave * PW;

    __shared__ float s_lds[16 * 161];     // +1 pad: b-stride 161 breaks conflicts
    for (int k = t; k < 16 * 161; k += 256) s_lds[k] = 0.f;

    float vs[NC][4];
    if (it > 0) {
        const float* vp = vsum + (size_t)(b0 + bcol) * CO + quad * 4;
#pragma unroll
        for (int c = 0; c < NC; ++c)
#pragma unroll
            for (int r = 0; r < 4; ++r) vs[c][r] = vp[c * 16 + r];
    }
    __syncthreads();

    floatx4 sacc[NC];
#pragma unroll
    for (int c = 0; c < NC; ++c) sacc[c] = (floatx4)(0.f);

    for (int pi = 0; pi < PW; ++pi) {
        const int p = pbase + pi;

        bf16x8 bfrag;
        if (lane < 32) {
            if (PC) {
                bfrag = load8(wsB + ((size_t)p * 16 + bt) * 32 + lane);
            } else {
                const float4* src = (const float4*)(poses +
                    ((size_t)(b0 + bcol) * NPOS + p) * IS + quad * 8);
                bfrag = pack8(src[0], src[1]);
            }
        } else bfrag = zero8();

        if (it == 0) {
            // coup = 0.1 for every c -> MFMA accumulator chains over p
#pragma unroll
            for (int c = 0; c < NC; ++c) {
                bf16x8 afrag;
                if (lane < 32) {
                    if (PC) afrag = load8(wsA + ((size_t)p * NC + c) * 32 + lane);
                    else {
                        const float4* src = (const float4*)(weight +
                            (size_t)(p * NC + c) * 256 + bcol * 16 + quad * 8);
                        afrag = pack8(src[0], src[1]);
                    }
                } else afrag = zero8();
                sacc[c] = __builtin_amdgcn_mfma_f32_16x16x32_bf16(afrag, bfrag, sacc[c], 0, 0, 0);
            }
        } else {
            floatx4 acc[NC];
#pragma unroll
            for (int c = 0; c < NC; ++c) {
                bf16x8 afrag;
                if (lane < 32) {
                    if (PC) afrag = load8(wsA + ((size_t)p * NC + c) * 32 + lane);
                    else {
                        const float4* src = (const float4*)(weight +
                            (size_t)(p * NC + c) * 256 + bcol * 16 + quad * 8);
                        afrag = pack8(src[0], src[1]);
                    }
                } else afrag = zero8();
                acc[c] = __builtin_amdgcn_mfma_f32_16x16x32_bf16(afrag, bfrag, (floatx4)(0.f), 0, 0, 0);
            }

            // logits: dot over o = (quad,reg); 4 FMA + 2 shfl per c
            float lg[NC];
            float mx = -1e30f;
#pragma unroll
            for (int c = 0; c < NC; ++c) {
                float pt = vs[c][0] * acc[c][0] + vs[c][1] * acc[c][1]
                         + vs[c][2] * acc[c][2] + vs[c][3] * acc[c][3];
                pt += __shfl_xor(pt, 16);
                pt += __shfl_xor(pt, 32);
                lg[c] = pt;
                mx = fmaxf(mx, pt);
            }
            float coup[NC];
            float sum = 0.f;
#pragma unroll
            for (int c = 0; c < NC; ++c) { coup[c] = __expf(lg[c] - mx); sum += coup[c]; }
            const float inv = 1.f / sum;
#pragma unroll
            for (int c = 0; c < NC; ++c) coup[c] *= inv;

            if (it == 2 && quad == 0) {
                float* cp = out_coup + (size_t)(b0 + bcol) * (NC * NPOS) + p;
#pragma unroll
                for (int c = 0; c < NC; ++c) cp[c * NPOS] = coup[c];
            }

#pragma unroll
            for (int c = 0; c < NC; ++c)
#pragma unroll
                for (int r = 0; r < 4; ++r) sacc[c][r] += coup[c] * acc[c][r];
        }
    }

    // merge the block's 4 waves in LDS
    const float scale = (it == 0) ? 0.1f : 1.f;
#pragma unroll
    for (int c = 0; c < NC; ++c)
#pragma unroll
        for (int r = 0; r < 4; ++r)
            atomicAdd(&s_lds[bcol * 161 + c * 16 + quad * 4 + r], scale * sacc[c][r]);
    __syncthreads();

    if (PART) {
        // plain coalesced stores to this block's private partial slice
        float* pp = sbuf + ((size_t)blockIdx.x * NB + b0) * CO;
        for (int k = t; k < 16 * CO; k += 256) {
            const int b = k / CO, j = k - b * CO;
            pp[(size_t)b * CO + j] = s_lds[b * 161 + j];
        }
    } else {
        for (int k = t; k < 16 * CO; k += 256) {
            const int b = k / CO, j = k - b * CO;
            unsafeAtomicAdd(&sbuf[(size_t)(b0 + b) * CO + j], s_lds[b * 161 + j]);
        }
    }
}

__global__ __launch_bounds__(256) void caps_squash_kernel(
    const float* __restrict__ rbias,   // [10, 16]
    float* __restrict__ sbuf,          // npart>0: part[npart][256][160]; else [256][160]
    float* __restrict__ vsum,          // [256, 10, 16]
    float* __restrict__ out_poses,     // [256, 10, 16]
    float* __restrict__ out_act,       // [256, 10]
    int it, int npart)
{
    const int b = blockIdx.x;
    const int t = threadIdx.x;
    if (t >= CO) return;
    const int c = t >> 4;

    const size_t idx = (size_t)b * CO + t;
    float s;
    if (npart > 0) {
        const float* p = sbuf + idx;
        const size_t stride = (size_t)NB * CO;
        float a0 = 0.f, a1 = 0.f, a2 = 0.f, a3 = 0.f;
        int px = 0;
        for (; px + 4 <= npart; px += 4) {
            a0 += p[(size_t)(px + 0) * stride];
            a1 += p[(size_t)(px + 1) * stride];
            a2 += p[(size_t)(px + 2) * stride];
            a3 += p[(size_t)(px + 3) * stride];
        }
        for (; px < npart; ++px) a0 += p[(size_t)px * stride];
        s = ((a0 + a1) + (a2 + a3)) + rbias[t];
    } else {
        s = sbuf[idx] + rbias[t];
    }

    float sq = s * s;
    sq += __shfl_xor(sq, 1);
    sq += __shfl_xor(sq, 2);
    sq += __shfl_xor(sq, 4);
    sq += __shfl_xor(sq, 8);
    const float f = (sq / (1.f + sq)) * rsqrtf(sq + CAPS_EPS);
    const float v = f * s;

    if (it < 2) {
        vsum[idx] += v;
        if (npart == 0) sbuf[idx] = 0.f;   // re-arm accumulator (legacy path)
    } else {
        out_poses[idx] = v;
        if ((t & 15) == 0) out_act[(size_t)b * NC + c] = sqrtf(f * f * sq + CAPS_EPS);
    }
}

extern "C" void kernel_launch(void* const* d_in, const int* in_sizes, int n_in,
                              void* d_out, int out_size, void* d_ws, size_t ws_size,
                              hipStream_t stream) {
    const float* poses  = (const float*)d_in[0];
    // d_in[1] (input_caps_activations) unused by the reference computation.
    const float* weight = (const float*)d_in[2];
    const float* rbias  = (const float*)d_in[3];

    float* out       = (float*)d_out;
    float* out_poses = out;                                   // 256*10*16
    float* out_act   = out + (size_t)NB * CO;                 // 256*10
    float* out_coup  = out_act + (size_t)NB * NC;             // 256*10*1152

    const size_t part_bytes = (size_t)PBLK * NB * CO * sizeof(float);  // 15.7 MB
    const size_t vsum_bytes = (size_t)NB * CO * sizeof(float);         // 160 KB
    const size_t frag_bytes = (size_t)(NA_SLOTS + NB_SLOTS) * sizeof(uint4);

    const bool part_ok = (ws_size >= part_bytes + vsum_bytes);
    const bool preconv = (ws_size >= part_bytes + vsum_bytes + frag_bytes);

    float* sbuf;
    float* vsum;
    uint4* wsA;
    if (part_ok) {
        sbuf = (float*)d_ws;                                  // part buffer
        vsum = sbuf + (size_t)PBLK * NB * CO;
        wsA  = (uint4*)((char*)d_ws + part_bytes + vsum_bytes);
        hipMemsetAsync(vsum, 0, vsum_bytes, stream);          // only vsum needs zero
    } else {
        sbuf = (float*)d_ws;                                  // legacy accumulator
        vsum = sbuf + (size_t)NB * CO;
        wsA  = (uint4*)((char*)d_ws + 2 * vsum_bytes);
        hipMemsetAsync(d_ws, 0, 2 * vsum_bytes, stream);
    }
    uint4* wsB = wsA + NA_SLOTS;

    if (preconv) {
        hipLaunchKernelGGL(preconv_kernel,
                           dim3((NA_SLOTS + NB_SLOTS) / 256), dim3(256), 0, stream,
                           poses, weight, wsA, wsB);
    }

    for (int it = 0; it < 3; ++it) {
        if (preconv) {
            hipLaunchKernelGGL((caps_votes_mfma<true, true>), dim3(PBLK, 16), dim3(256), 0, stream,
                               poses, weight, wsA, wsB, vsum, sbuf, out_coup, it);
        } else if (part_ok) {
            hipLaunchKernelGGL((caps_votes_mfma<false, true>), dim3(PBLK, 16), dim3(256), 0, stream,
                               poses, weight, wsA, wsB, vsum, sbuf, out_coup, it);
        } else {
            hipLaunchKernelGGL((caps_votes_mfma<false, false>), dim3(PBLK, 16), dim3(256), 0, stream,
                               poses, weight, wsA, wsB, vsum, sbuf, out_coup, it);
        }
        hipLaunchKernelGGL(caps_squash_kernel, dim3(NB), dim3(256), 0, stream,
                           rbias, sbuf, vsum, out_poses, out_act, it,
                           part_ok ? PBLK : 0);
    }
}

// Round 2
// 263.518 us; speedup vs baseline: 1.6128x; 1.6128x over previous
//
#include <hip/hip_runtime.h>

// CapsClass2d dynamic routing — MFMA (bf16), divergence-free loads.
// b=256, P=1152, C=10, os=is=16, 3 iterations.
// logits telescope: logits_k = dot(sum_{j<k} v_j, votes) -> only vsum state.
//
// R1 post-mortem: kernel is LATENCY-bound (545 GB/s eff, all pipes idle).
// Cause theory: every frag load sat under `if(lane<32) load else zero` —
// exec-masked regions + phi-with-zero force per-load waitcnt -> loads
// serialize at one ~700cy latency each. Fixes:
//   1. All-lane unconditional loads; lanes>=32 read a 512B ZERO PAGE via
//      branchless pointer select (no exec divergence, loads batch).
//   2. it=0 needs only sum_p votes -> pack (p, p+1) into lower/upper K
//      halves of one 16x16x32 MFMA: all lanes real data, half the loads
//      and half the MFMAs, zero padding gone.
//   3. PW=6 -> grid 768 = exactly 3 blocks/CU (one generation at the
//      3-wave/EU register budget).
//   4. out_coup via LDS -> coalesced 24-float runs (was 4B scatters with
//      16x line-RMW amplification).
// Merge: per-block LDS -> plain stores to part[PBLK][b][j]; squash reduces.

#define NPOS 1152
#define NC 10
#define OS 16
#define IS 16
#define NB 256
#define CO (NC * OS)            // 160
#define CAPS_EPS 1e-8f
#define PW 6                    // positions per wave (even: it0 pairs)
#define PBLK (NPOS / (4 * PW))  // 48 p-superblocks
#define PPB (4 * PW)            // 24 positions per block
#define NA_SLOTS (NPOS * NC * 32)   // 368640 A-frag lane slots
#define NB_SLOTS (NPOS * 16 * 32)   // 589824 B-frag lane slots

typedef __attribute__((ext_vector_type(8))) short bf16x8;
typedef __attribute__((ext_vector_type(4))) float floatx4;

__device__ __forceinline__ unsigned f2bf_rne(float x) {
    union { float f; unsigned u; } v; v.f = x;
    return (v.u + 0x7FFFu + ((v.u >> 16) & 1u)) >> 16;
}

__device__ __forceinline__ bf16x8 pack8(float4 a, float4 b) {
    union { unsigned u[4]; bf16x8 v; } r;
    r.u[0] = f2bf_rne(a.x) | (f2bf_rne(a.y) << 16);
    r.u[1] = f2bf_rne(a.z) | (f2bf_rne(a.w) << 16);
    r.u[2] = f2bf_rne(b.x) | (f2bf_rne(b.y) << 16);
    r.u[3] = f2bf_rne(b.z) | (f2bf_rne(b.w) << 16);
    return r.v;
}

__device__ __forceinline__ bf16x8 zero8() {
    union { unsigned u[4]; bf16x8 v; } r;
    r.u[0] = r.u[1] = r.u[2] = r.u[3] = 0u;
    return r.v;
}

__device__ __forceinline__ bf16x8 load8(const uint4* p) {
    union { uint4 u; bf16x8 v; } r; r.u = *p; return r.v;
}

// Pre-convert W and poses into bf16 fragment-layout buffers.
__global__ __launch_bounds__(256) void preconv_kernel(
    const float* __restrict__ poses, const float* __restrict__ weight,
    uint4* __restrict__ wsA, uint4* __restrict__ wsB)
{
    const int gid = blockIdx.x * 256 + threadIdx.x;
    if (gid < NA_SLOTS) {
        const int L = gid & 31, pc = gid >> 5;          // pc = p*10+c
        const int o = L & 15, q = L >> 4;
        const float4* src = (const float4*)(weight + (size_t)pc * 256 + o * 16 + q * 8);
        union { uint4 u; bf16x8 v; } cv;
        cv.v = pack8(src[0], src[1]);
        wsA[gid] = cv.u;
    } else {
        const int s = gid - NA_SLOTS;
        if (s < NB_SLOTS) {
            const int L = s & 31, pb = s >> 5;
            const int bt = pb & 15, p = pb >> 4;
            const int bl = L & 15, q = L >> 4;
            const float4* src = (const float4*)(poses +
                ((size_t)(bt * 16 + bl) * NPOS + p) * IS + q * 8);
            union { uint4 u; bf16x8 v; } cv;
            cv.v = pack8(src[0], src[1]);
            wsB[s] = cv.u;
        }
    }
}

// PC: use preconverted frag buffers. PART: partial-store merge (else atomics).
template <bool PC, bool PART>
__global__ __launch_bounds__(256, 3) void caps_votes_mfma(
    const float* __restrict__ poses, const float* __restrict__ weight,
    const uint4* __restrict__ wsA, const uint4* __restrict__ wsB,
    const uint4* __restrict__ zp,
    const float* __restrict__ vsum, float* __restrict__ sbuf,
    float* __restrict__ out_coup, int it)
{
    const int t    = threadIdx.x;
    const int wave = t >> 6, lane = t & 63;
    const int bcol = lane & 15, quad = lane >> 4;
    const int bt   = blockIdx.y;          // b-tile (16 batches)
    const int b0   = bt * 16;
    const int pbase = blockIdx.x * PPB + wave * PW;
    const int li   = lane & 31;
    const bool lo  = lane < 32;

    __shared__ float s_lds[16 * 161];     // +1 pad: b-stride 161 breaks conflicts
    __shared__ float coup_lds[16 * NC * PPB];   // it=2 coup staging (15 KB)
    for (int k = t; k < 16 * 161; k += 256) s_lds[k] = 0.f;

    float vs[NC][4];
    if (it > 0) {
        const float* vp = vsum + (size_t)(b0 + bcol) * CO + quad * 4;
#pragma unroll
        for (int c = 0; c < NC; ++c)
#pragma unroll
            for (int r = 0; r < 4; ++r) vs[c][r] = vp[c * 16 + r];
    }
    __syncthreads();

    floatx4 sacc[NC];
#pragma unroll
    for (int c = 0; c < NC; ++c) sacc[c] = (floatx4)(0.f);

    if (it == 0) {
        if (PC) {
            // p-pairing: lower 32 lanes carry p, upper 32 carry p+1.
            // K halves of the 16x16x32 MFMA sum both -> sacc = sum votes.
            const size_t lpo = (size_t)(lane >> 5);
            for (int pi = 0; pi < PW; pi += 2) {
                const size_t p = (size_t)(pbase + pi) + lpo;
                const bf16x8 bfrag = load8(wsB + (p * 16 + bt) * 32 + li);
#pragma unroll
                for (int c = 0; c < NC; ++c) {
                    const bf16x8 a = load8(wsA + (p * NC + c) * 32 + li);
                    sacc[c] = __builtin_amdgcn_mfma_f32_16x16x32_bf16(a, bfrag, sacc[c], 0, 0, 0);
                }
            }
        } else {
            for (int pi = 0; pi < PW; ++pi) {
                const int p = pbase + pi;
                bf16x8 bfrag;
                if (lo) {
                    const float4* src = (const float4*)(poses +
                        ((size_t)(b0 + bcol) * NPOS + p) * IS + quad * 8);
                    bfrag = pack8(src[0], src[1]);
                } else bfrag = zero8();
#pragma unroll
                for (int c = 0; c < NC; ++c) {
                    bf16x8 afrag;
                    if (lo) {
                        const float4* src = (const float4*)(weight +
                            (size_t)(p * NC + c) * 256 + bcol * 16 + quad * 8);
                        afrag = pack8(src[0], src[1]);
                    } else afrag = zero8();
                    sacc[c] = __builtin_amdgcn_mfma_f32_16x16x32_bf16(afrag, bfrag, sacc[c], 0, 0, 0);
                }
            }
        }
    } else {
        for (int pi = 0; pi < PW; ++pi) {
            const int p = pbase + pi;

            bf16x8 bfrag;
            if (PC) {
                const uint4* bp = lo ? (wsB + ((size_t)p * 16 + bt) * 32 + li)
                                     : (zp + li);
                bfrag = load8(bp);
            } else {
                if (lo) {
                    const float4* src = (const float4*)(poses +
                        ((size_t)(b0 + bcol) * NPOS + p) * IS + quad * 8);
                    bfrag = pack8(src[0], src[1]);
                } else bfrag = zero8();
            }

            floatx4 acc[NC];
#pragma unroll
            for (int c = 0; c < NC; ++c) {
                bf16x8 afrag;
                if (PC) {
                    const uint4* ap = lo ? (wsA + ((size_t)p * NC + c) * 32 + li)
                                         : (zp + li);
                    afrag = load8(ap);
                } else {
                    if (lo) {
                        const float4* src = (const float4*)(weight +
                            (size_t)(p * NC + c) * 256 + bcol * 16 + quad * 8);
                        afrag = pack8(src[0], src[1]);
                    } else afrag = zero8();
                }
                acc[c] = __builtin_amdgcn_mfma_f32_16x16x32_bf16(afrag, bfrag, (floatx4)(0.f), 0, 0, 0);
            }

            // logits: dot over o = (quad,reg); 4 FMA + 2 shfl per c
            float lg[NC];
            float mx = -1e30f;
#pragma unroll
            for (int c = 0; c < NC; ++c) {
                float pt = vs[c][0] * acc[c][0] + vs[c][1] * acc[c][1]
                         + vs[c][2] * acc[c][2] + vs[c][3] * acc[c][3];
                pt += __shfl_xor(pt, 16);
                pt += __shfl_xor(pt, 32);
                lg[c] = pt;
                mx = fmaxf(mx, pt);
            }
            float coup[NC];
            float sum = 0.f;
#pragma unroll
            for (int c = 0; c < NC; ++c) { coup[c] = __expf(lg[c] - mx); sum += coup[c]; }
            const float inv = 1.f / sum;
#pragma unroll
            for (int c = 0; c < NC; ++c) coup[c] *= inv;

            if (it == 2 && quad == 0) {
                // stage to LDS; coalesced global write after the barrier
                const int pp = wave * PW + pi;
#pragma unroll
                for (int c = 0; c < NC; ++c)
                    coup_lds[(bcol * NC + c) * PPB + pp] = coup[c];
            }

#pragma unroll
            for (int c = 0; c < NC; ++c)
#pragma unroll
                for (int r = 0; r < 4; ++r) sacc[c][r] += coup[c] * acc[c][r];
        }
    }

    // merge the block's 4 waves in LDS
    const float scale = (it == 0) ? 0.1f : 1.f;
#pragma unroll
    for (int c = 0; c < NC; ++c)
#pragma unroll
        for (int r = 0; r < 4; ++r)
            atomicAdd(&s_lds[bcol * 161 + c * 16 + quad * 4 + r], scale * sacc[c][r]);
    __syncthreads();

    if (PART) {
        // plain coalesced stores to this block's private partial slice
        float* pp = sbuf + ((size_t)blockIdx.x * NB + b0) * CO;
        for (int k = t; k < 16 * CO; k += 256) {
            const int b = k / CO, j = k - b * CO;
            pp[(size_t)b * CO + j] = s_lds[b * 161 + j];
        }
    } else {
        for (int k = t; k < 16 * CO; k += 256) {
            const int b = k / CO, j = k - b * CO;
            unsafeAtomicAdd(&sbuf[(size_t)(b0 + b) * CO + j], s_lds[b * 161 + j]);
        }
    }

    if (it == 2) {
        // coalesced coup write: 24 consecutive p per (b,c)
        const int p0 = blockIdx.x * PPB;
        for (int k = t; k < 16 * NC * PPB; k += 256) {
            const int pp = k % PPB;
            const int bc = k / PPB;
            const int b = bc / NC, c = bc - b * NC;
            out_coup[(size_t)(b0 + b) * (NC * NPOS) + (size_t)c * NPOS + p0 + pp] =
                coup_lds[k];
        }
    }
}

__global__ __launch_bounds__(256) void caps_squash_kernel(
    const float* __restrict__ rbias,   // [10, 16]
    float* __restrict__ sbuf,          // npart>0: part[npart][256][160]; else [256][160]
    float* __restrict__ vsum,          // [256, 10, 16]
    float* __restrict__ out_poses,     // [256, 10, 16]
    float* __restrict__ out_act,       // [256, 10]
    int it, int npart)
{
    const int b = blockIdx.x;
    const int t = threadIdx.x;
    if (t >= CO) return;
    const int c = t >> 4;

    const size_t idx = (size_t)b * CO + t;
    float s;
    if (npart > 0) {
        const float* p = sbuf + idx;
        const size_t stride = (size_t)NB * CO;
        float a0 = 0.f, a1 = 0.f, a2 = 0.f, a3 = 0.f;
        int px = 0;
        for (; px + 4 <= npart; px += 4) {
            a0 += p[(size_t)(px + 0) * stride];
            a1 += p[(size_t)(px + 1) * stride];
            a2 += p[(size_t)(px + 2) * stride];
            a3 += p[(size_t)(px + 3) * stride];
        }
        for (; px < npart; ++px) a0 += p[(size_t)px * stride];
        s = ((a0 + a1) + (a2 + a3)) + rbias[t];
    } else {
        s = sbuf[idx] + rbias[t];
    }

    float sq = s * s;
    sq += __shfl_xor(sq, 1);
    sq += __shfl_xor(sq, 2);
    sq += __shfl_xor(sq, 4);
    sq += __shfl_xor(sq, 8);
    const float f = (sq / (1.f + sq)) * rsqrtf(sq + CAPS_EPS);
    const float v = f * s;

    if (it < 2) {
        vsum[idx] += v;
        if (npart == 0) sbuf[idx] = 0.f;   // re-arm accumulator (legacy path)
    } else {
        out_poses[idx] = v;
        if ((t & 15) == 0) out_act[(size_t)b * NC + c] = sqrtf(f * f * sq + CAPS_EPS);
    }
}

extern "C" void kernel_launch(void* const* d_in, const int* in_sizes, int n_in,
                              void* d_out, int out_size, void* d_ws, size_t ws_size,
                              hipStream_t stream) {
    const float* poses  = (const float*)d_in[0];
    // d_in[1] (input_caps_activations) unused by the reference computation.
    const float* weight = (const float*)d_in[2];
    const float* rbias  = (const float*)d_in[3];

    float* out       = (float*)d_out;
    float* out_poses = out;                                   // 256*10*16
    float* out_act   = out + (size_t)NB * CO;                 // 256*10
    float* out_coup  = out_act + (size_t)NB * NC;             // 256*10*1152

    const size_t part_bytes = (size_t)PBLK * NB * CO * sizeof(float);  // 7.9 MB
    const size_t vsum_bytes = (size_t)NB * CO * sizeof(float);         // 160 KB
    const size_t zp_bytes   = 512;                                     // 32 uint4 of zeros
    const size_t frag_bytes = (size_t)(NA_SLOTS + NB_SLOTS) * sizeof(uint4);

    const size_t need_part = part_bytes + vsum_bytes + zp_bytes;
    const size_t need_full = need_part + frag_bytes;

    const bool part_ok = (ws_size >= need_part);
    const bool preconv = (ws_size >= need_full);

    float* sbuf;
    float* vsum;
    uint4* zp;
    uint4* wsA;
    if (part_ok) {
        sbuf = (float*)d_ws;                                  // part buffer
        vsum = sbuf + (size_t)PBLK * NB * CO;
        zp   = (uint4*)((char*)d_ws + part_bytes + vsum_bytes);
        wsA  = (uint4*)((char*)d_ws + need_part);
        // zero vsum + zero page in one memset
        hipMemsetAsync(vsum, 0, vsum_bytes + zp_bytes, stream);
    } else {
        sbuf = (float*)d_ws;                                  // legacy accumulator
        vsum = sbuf + (size_t)NB * CO;
        zp   = (uint4*)d_ws;                                  // unused in legacy path
        wsA  = (uint4*)((char*)d_ws + 2 * vsum_bytes);
        hipMemsetAsync(d_ws, 0, 2 * vsum_bytes, stream);
    }
    uint4* wsB = wsA + NA_SLOTS;

    if (preconv) {
        hipLaunchKernelGGL(preconv_kernel,
                           dim3((NA_SLOTS + NB_SLOTS) / 256), dim3(256), 0, stream,
                           poses, weight, wsA, wsB);
    }

    for (int it = 0; it < 3; ++it) {
        if (preconv) {
            hipLaunchKernelGGL((caps_votes_mfma<true, true>), dim3(PBLK, 16), dim3(256), 0, stream,
                               poses, weight, wsA, wsB, zp, vsum, sbuf, out_coup, it);
        } else if (part_ok) {
            hipLaunchKernelGGL((caps_votes_mfma<false, true>), dim3(PBLK, 16), dim3(256), 0, stream,
                               poses, weight, wsA, wsB, zp, vsum, sbuf, out_coup, it);
        } else {
            hipLaunchKernelGGL((caps_votes_mfma<false, false>), dim3(PBLK, 16), dim3(256), 0, stream,
                               poses, weight, wsA, wsB, zp, vsum, sbuf, out_coup, it);
        }
        hipLaunchKernelGGL(caps_squash_kernel, dim3(NB), dim3(256), 0, stream,
                           rbias, sbuf, vsum, out_poses, out_act, it,
                           part_ok ? PBLK : 0);
    }
}